// Round 1
// baseline (177.722 us; speedup 1.0000x reference)
//
#include <hip/hip_runtime.h>

// YOLO loss, S=14 grid, B=2 boxes, C=20 classes, N_EL=30.
// One block per batch row (4096 blocks x 256 threads).
// Strategy: never materialize the target tensor. Each cell's target row is
// determined by the LAST box (scatter .set duplicate semantics) landing in it.

#define SGRID 14
#define CELLS 196            // 14*14
#define NEL 30               // B*5 + C
#define NBOX 16
#define PRED_PER_BATCH (CELLS * NEL)   // 5880

__global__ __launch_bounds__(256) void yolo_loss_kernel(
    const float* __restrict__ pred,     // [batch, 5880]
    const float* __restrict__ boxes,    // [batch, 16, 4]
    const int*   __restrict__ classes,  // [batch, 16]
    float* __restrict__ out)
{
    __shared__ float s_pred[PRED_PER_BATCH];       // 23520 B
    __shared__ float s_dx[NBOX], s_dy[NBOX], s_w[NBOX], s_h[NBOX];
    __shared__ int   s_cell[NBOX], s_cls[NBOX];
    __shared__ float s_wsum[4];

    const int batch = blockIdx.x;
    const int tid   = threadIdx.x;

    // ---- stage pred row: 1470 float4, coalesced ----
    {
        const float4* src = (const float4*)(pred + (size_t)batch * PRED_PER_BATCH);
        float4* dst = (float4*)s_pred;
        #pragma unroll
        for (int i = 0; i < PRED_PER_BATCH / 4 / 256 + 1; ++i) {
            int idx = tid + i * 256;
            if (idx < PRED_PER_BATCH / 4) dst[idx] = src[idx];
        }
    }

    // ---- encode the 16 boxes (threads 0..15) ----
    if (tid < NBOX) {
        const float* b = boxes + ((size_t)batch * NBOX + tid) * 4;
        float x1 = b[0], y1 = b[1], x2 = b[2], y2 = b[3];
        // match jnp: cell = float32(1.0/14.0); f = c / cell  (division!)
        const float cellw = (float)(1.0 / 14.0);
        float w  = x2 - x1,            h  = y2 - y1;
        float cx = (x1 + x2) * 0.5f,   cy = (y1 + y2) * 0.5f;
        float fx = cx / cellw,         fy = cy / cellw;
        float fi = fminf(fmaxf(ceilf(fx) - 1.0f, 0.0f), 13.0f);
        float fj = fminf(fmaxf(ceilf(fy) - 1.0f, 0.0f), 13.0f);
        s_dx[tid]   = fx - fi;
        s_dy[tid]   = fy - fj;
        s_w[tid]    = w;
        s_h[tid]    = h;
        s_cell[tid] = (int)fj * SGRID + (int)fi;
        s_cls[tid]  = classes[batch * NBOX + tid];
    }
    __syncthreads();

    float loss = 0.0f;
    if (tid < CELLS) {
        // last box (in index order) mapping to this cell wins (scatter .set)
        int k = -1;
        #pragma unroll
        for (int b = 0; b < NBOX; ++b)
            if (s_cell[b] == tid) k = b;

        const float* p = s_pred + tid * NEL;
        if (k < 0) {
            // no-object cell: 0.5 * (p4^2 + p9^2)
            loss = 0.5f * (p[4] * p[4] + p[9] * p[9]);
        } else {
            const float dx = s_dx[k], dy = s_dy[k];
            const float w  = s_w[k],  h  = s_h[k];
            const int cls  = s_cls[k];

            // class loss over channels 10..29; one-hot at 9+cls (cls=0 -> ch9,
            // i.e. contributes nothing here -- faithful off-by-one)
            const int hot = 9 + cls;
            #pragma unroll
            for (int c = 10; c < 30; ++c) {
                float t = (c == hot) ? 1.0f : 0.0f;
                float d = p[c] - t;
                loss += d * d;
            }

            // corner-format "IoU" of (dx,dy,w,h) rows verbatim, per reference
            float iou[2];
            const float area_t = (w - dx) * (h - dy);
            #pragma unroll
            for (int i = 0; i < 2; ++i) {
                const float* a = p + i * 5;
                float ltx = fmaxf(a[0], dx), lty = fmaxf(a[1], dy);
                float rbx = fminf(a[2], w),  rby = fminf(a[3], h);
                float wi = fmaxf(rbx - ltx, 0.0f);
                float hi = fmaxf(rby - lty, 0.0f);
                float inter  = wi * hi;
                float area_a = (a[2] - a[0]) * (a[3] - a[1]);
                float uni    = area_a + area_t - inter;
                iou[i] = inter / ((uni == 0.0f) ? 1.0f : uni);
            }
            // argmax over pred axis, tie -> index 0; both target cols identical
            int r = (iou[1] > iou[0]) ? 1 : 0;
            const float* a = p + r * 5;

            // contain loss: (conf - 1)^2 on responsible box
            float dc = a[4] - 1.0f;
            loss += dc * dc;

            // loc loss * L_COORD
            float lx = a[0] - dx;
            float ly = a[1] - dy;
            float lw = sqrtf(a[2]) - sqrtf(w);
            float lh = sqrtf(a[3]) - sqrtf(h);
            loss += 5.0f * (lx * lx + ly * ly + lw * lw + lh * lh);
        }
    }

    // ---- block reduction: wave64 shfl, then cross-wave via LDS ----
    #pragma unroll
    for (int off = 32; off > 0; off >>= 1)
        loss += __shfl_down(loss, off, 64);
    const int wave = tid >> 6;
    if ((tid & 63) == 0) s_wsum[wave] = loss;
    __syncthreads();
    if (tid == 0) {
        float tot = s_wsum[0] + s_wsum[1] + s_wsum[2] + s_wsum[3];
        atomicAdd(out, tot);
    }
}

extern "C" void kernel_launch(void* const* d_in, const int* in_sizes, int n_in,
                              void* d_out, int out_size, void* d_ws, size_t ws_size,
                              hipStream_t stream) {
    const float* pred    = (const float*)d_in[0];
    const float* boxes   = (const float*)d_in[1];
    const int*   classes = (const int*)d_in[2];
    float* out = (float*)d_out;

    const int batch = in_sizes[0] / PRED_PER_BATCH;   // 4096

    // d_out is poisoned 0xAA before every timed launch -> zero it (capture-safe)
    hipMemsetAsync(d_out, 0, sizeof(float) * out_size, stream);

    yolo_loss_kernel<<<dim3(batch), dim3(256), 0, stream>>>(pred, boxes, classes, out);
}

// Round 2
// 159.068 us; speedup vs baseline: 1.1173x; 1.1173x over previous
//
#include <hip/hip_runtime.h>

// YOLO loss, S=14, B=2, C=20, N_EL=30, batch=4096, 16 boxes/row.
// 3-stage pipeline, no LDS staging, no same-address atomics:
//   1) memset winner map to -1 (0xFF), encode kernel: thread per (batch,box)
//      writes box params and atomicMax's its box index into winner[batch][cell]
//      (max index == last-wins, matching np scatter .set semantics).
//   2) main kernel: thread per cell, divergent fast path for no-object cells
//      (only p[4],p[9] needed), wave shfl-reduce, one plain store per wave.
//   3) reduce kernel: 1 block sums the per-wave partials into out[0].

#define SGRID 14
#define CELLS 196
#define NEL 30
#define NBOX 16
#define PRED_PER_BATCH (CELLS * NEL)   // 5880

__global__ void encode_kernel(const float* __restrict__ boxes,
                              const int*   __restrict__ classes,
                              int*   __restrict__ winner,   // [batch*196], pre-set to -1
                              float* __restrict__ params,   // [batch*16*8]
                              int nbb)                      // batch*16
{
    int t = blockIdx.x * blockDim.x + threadIdx.x;
    if (t >= nbb) return;
    int b = t >> 4;                       // batch row
    int k = t & 15;                       // box index
    float4 bx = ((const float4*)boxes)[t];
    float w  = bx.z - bx.x,  h  = bx.w - bx.y;
    float cx = (bx.x + bx.z) * 0.5f, cy = (bx.y + bx.w) * 0.5f;
    const float cellw = (float)(1.0 / 14.0);   // match jnp: divide by float32(1/14)
    float fx = cx / cellw, fy = cy / cellw;
    float fi = fminf(fmaxf(ceilf(fx) - 1.0f, 0.0f), 13.0f);
    float fj = fminf(fmaxf(ceilf(fy) - 1.0f, 0.0f), 13.0f);
    int cell = (int)fj * SGRID + (int)fi;
    float* pr = params + (size_t)t * 8;
    pr[0] = fx - fi;  pr[1] = fy - fj;
    pr[2] = w;        pr[3] = h;
    pr[4] = (float)classes[t];
    atomicMax(&winner[b * CELLS + cell], k);
}

__global__ __launch_bounds__(256) void yolo_main_kernel(
    const float* __restrict__ pred,      // [batch*5880]
    const int*   __restrict__ winner,    // [batch*196]
    const float* __restrict__ params,    // [batch*16*8]
    float* __restrict__ partials,        // one float per wave
    int total)                           // batch*196
{
    int idx = blockIdx.x * 256 + threadIdx.x;
    float loss = 0.0f;
    if (idx < total) {
        int b    = idx / CELLS;          // magic-mul div
        const float* p = pred + (size_t)idx * NEL;   // (b*196+cell)*30 == b*5880+cell*30
        int k = winner[idx];             // coalesced 4B per lane
        if (k < 0) {
            // no-object: 0.5 * (p4^2 + p9^2) -- two 8B loads only
            float2 a = *(const float2*)(p + 4);   // p4,p5
            float2 c = *(const float2*)(p + 8);   // p8,p9
            loss = 0.5f * (a.x * a.x + c.y * c.y);
        } else {
            float pp[NEL];
            #pragma unroll
            for (int j = 0; j < NEL / 2; ++j)
                ((float2*)pp)[j] = ((const float2*)p)[j];
            const float* pr = params + (size_t)(b * NBOX + k) * 8;
            float dx = pr[0], dy = pr[1], w = pr[2], h = pr[3];
            int cls = (int)pr[4];

            // class loss, channels 10..29; one-hot at 9+cls (cls=0 -> ch9:
            // faithful off-by-one, contributes nothing here)
            int hot = 9 + cls;
            #pragma unroll
            for (int c = 10; c < NEL; ++c) {
                float t = (c == hot) ? 1.0f : 0.0f;
                float d = pp[c] - t;
                loss += d * d;
            }

            // corner-format "IoU" of (dx,dy,w,h) rows verbatim
            float area_t = (w - dx) * (h - dy);
            float iou[2];
            #pragma unroll
            for (int i = 0; i < 2; ++i) {
                const float* a = pp + i * 5;
                float ltx = fmaxf(a[0], dx), lty = fmaxf(a[1], dy);
                float rbx = fminf(a[2], w),  rby = fminf(a[3], h);
                float wi = fmaxf(rbx - ltx, 0.0f);
                float hi = fmaxf(rby - lty, 0.0f);
                float inter  = wi * hi;
                float area_a = (a[2] - a[0]) * (a[3] - a[1]);
                float uni    = area_a + area_t - inter;
                iou[i] = inter / ((uni == 0.0f) ? 1.0f : uni);
            }
            int r = (iou[1] > iou[0]) ? 1 : 0;   // argmax tie -> 0
            const float* a = pp + r * 5;

            float dc = a[4] - 1.0f;              // contain
            loss += dc * dc;
            float lx = a[0] - dx;                // loc * L_COORD
            float ly = a[1] - dy;
            float lw = sqrtf(a[2]) - sqrtf(w);
            float lh = sqrtf(a[3]) - sqrtf(h);
            loss += 5.0f * (lx * lx + ly * ly + lw * lw + lh * lh);
        }
    }

    // wave64 reduction, one plain store per wave (no atomics)
    #pragma unroll
    for (int off = 32; off > 0; off >>= 1)
        loss += __shfl_down(loss, off, 64);
    if ((threadIdx.x & 63) == 0)
        partials[(blockIdx.x * 256 + threadIdx.x) >> 6] = loss;
}

__global__ __launch_bounds__(256) void reduce_kernel(
    const float* __restrict__ partials, float* __restrict__ out, int n)
{
    float s = 0.0f;
    for (int i = threadIdx.x; i < n; i += 256) s += partials[i];
    #pragma unroll
    for (int off = 32; off > 0; off >>= 1)
        s += __shfl_down(s, off, 64);
    __shared__ float w4[4];
    if ((threadIdx.x & 63) == 0) w4[threadIdx.x >> 6] = s;
    __syncthreads();
    if (threadIdx.x == 0) out[0] = w4[0] + w4[1] + w4[2] + w4[3];
}

extern "C" void kernel_launch(void* const* d_in, const int* in_sizes, int n_in,
                              void* d_out, int out_size, void* d_ws, size_t ws_size,
                              hipStream_t stream) {
    const float* pred    = (const float*)d_in[0];
    const float* boxes   = (const float*)d_in[1];
    const int*   classes = (const int*)d_in[2];
    float* out = (float*)d_out;

    const int batch = in_sizes[0] / PRED_PER_BATCH;   // 4096
    const int total = batch * CELLS;                  // 802816
    const int nbb   = batch * NBOX;                   // 65536

    // ws layout: winner [total] int | params [nbb*8] float | partials [nwaves]
    int*   winner   = (int*)d_ws;
    float* params   = (float*)((char*)d_ws + (size_t)total * sizeof(int));
    float* partials = params + (size_t)nbb * 8;
    const int mgrid  = (total + 255) / 256;
    const int nwaves = mgrid * 4;                     // waves in main kernel

    hipMemsetAsync(winner, 0xFF, (size_t)total * sizeof(int), stream);
    encode_kernel<<<dim3((nbb + 255) / 256), dim3(256), 0, stream>>>(
        boxes, classes, winner, params, nbb);
    yolo_main_kernel<<<dim3(mgrid), dim3(256), 0, stream>>>(
        pred, winner, params, partials, total);
    reduce_kernel<<<dim3(1), dim3(256), 0, stream>>>(partials, out, nwaves);
}